// Round 2
// baseline (2598.078 us; speedup 1.0000x reference)
//
#include <hip/hip_runtime.h>
#include <hip/hip_bf16.h>
#include <cstdint>
#include <cstddef>

#define DEV __device__ __forceinline__

// ---------------- problem constants ----------------
constexpr int BB    = 32;
constexpr int SEQ   = 1024;
constexpr int HID   = 1152;
constexpr int HEADS = 12;
constexpr int KVH   = 4;
constexpr int HD    = 96;
constexpr int KVC   = 384;   // KVH*HD
constexpr int MLPD  = 4608;
constexpr int ROWS  = BB * SEQ;          // 32768
constexpr int MODW  = 6 * HID;           // 6912

typedef __attribute__((ext_vector_type(8))) short short8;
typedef __attribute__((ext_vector_type(4))) float f32x4;

// ---------------- helpers ----------------
DEV float bfu2f(unsigned short u) {
    unsigned v = ((unsigned)u) << 16;
    return __builtin_bit_cast(float, v);
}
DEV unsigned short f2bf16u(float f) {
    unsigned u = __builtin_bit_cast(unsigned, f);
    u += 0x7FFFu + ((u >> 16) & 1u);   // RNE
    return (unsigned short)(u >> 16);
}
DEV unsigned pack2(float a, float b) {
    return (unsigned)f2bf16u(a) | ((unsigned)f2bf16u(b) << 16);
}
DEV float gelu_tanh(float x) {
    float x3 = x * x * x;
    float t = tanhf(0.7978845608028654f * (x + 0.044715f * x3));
    return 0.5f * x * (1.f + t);
}

// block reduce of two floats, blockDim.x == 256
DEV void block_reduce2(float& a, float& b) {
    #pragma unroll
    for (int off = 32; off > 0; off >>= 1) {
        a += __shfl_down(a, off, 64);
        b += __shfl_down(b, off, 64);
    }
    __shared__ float sa[4], sb[4];
    int w = threadIdx.x >> 6;
    if ((threadIdx.x & 63) == 0) { sa[w] = a; sb[w] = b; }
    __syncthreads();
    a = sa[0] + sa[1] + sa[2] + sa[3];
    b = sb[0] + sb[1] + sb[2] + sb[3];
    __syncthreads();
}

// ---------------- weight transpose + bf16 convert ----------------
// in: fp32 (K,N) row-major -> out: bf16 (N,K) row-major
__global__ void k_transpose_bf16(const float* __restrict__ in,
                                 unsigned short* __restrict__ out, int K, int N) {
    __shared__ float tile[32][33];
    int kb = blockIdx.x * 32;
    int nb = blockIdx.y * 32;
    int tx = threadIdx.x, ty = threadIdx.y;   // (32, 8)
    #pragma unroll
    for (int j = 0; j < 4; j++) {
        int k = kb + ty + j * 8;
        tile[ty + j * 8][tx] = (k < K && nb + tx < N) ? in[(size_t)k * N + nb + tx] : 0.f;
    }
    __syncthreads();
    #pragma unroll
    for (int j = 0; j < 4; j++) {
        int n = nb + ty + j * 8;
        if (n < N && kb + tx < K)
            out[(size_t)n * K + kb + tx] = f2bf16u(tile[tx][ty + j * 8]);
    }
}

// ---------------- adaLN: mod = silu(c) @ adaln_w + adaln_b ----------------
__global__ __launch_bounds__(256) void k_mod(const float* __restrict__ cvec,
                                             const float* __restrict__ w,
                                             const float* __restrict__ bias,
                                             float* __restrict__ mod) {
    const int b = blockIdx.y;
    const int col = blockIdx.x * 256 + threadIdx.x;
    __shared__ float sc[HID];
    for (int i = threadIdx.x; i < HID; i += 256) {
        float v = cvec[b * HID + i];
        sc[i] = v / (1.f + __expf(-v));
    }
    __syncthreads();
    float acc = bias[col];
    for (int k = 0; k < HID; k++) acc += sc[k] * w[(size_t)k * MODW + col];
    mod[(size_t)b * MODW + col] = acc;
}

// ---------------- layernorm + modulate -> bf16 ----------------
// x is a CHUNK base (row 0 = global row r0); out is chunk base.
__global__ __launch_bounds__(256) void k_ln_mod(const float* __restrict__ x,
                                                const float* __restrict__ mod,
                                                int shift_chunk, int scale_chunk,
                                                unsigned short* __restrict__ out,
                                                int r0) {
    const size_t row = blockIdx.x;
    const int b = (int)((r0 + row) >> 10);
    const float4* xr = (const float4*)(x + row * HID);
    const int t = threadIdx.x;
    float4 v0 = xr[t];
    float4 v1 = make_float4(0.f, 0.f, 0.f, 0.f);
    if (t < 32) v1 = xr[256 + t];
    float s  = v0.x + v0.y + v0.z + v0.w + v1.x + v1.y + v1.z + v1.w;
    float s2 = v0.x*v0.x + v0.y*v0.y + v0.z*v0.z + v0.w*v0.w
             + v1.x*v1.x + v1.y*v1.y + v1.z*v1.z + v1.w*v1.w;
    block_reduce2(s, s2);
    const float mean = s * (1.f / HID);
    float var = s2 * (1.f / HID) - mean * mean;
    const float rstd = rsqrtf(fmaxf(var, 0.f) + 1e-6f);
    const float* shiftp = mod + (size_t)b * MODW + shift_chunk * HID;
    const float* scalep = mod + (size_t)b * MODW + scale_chunk * HID;
    {
        float4 sc = *(const float4*)(scalep + 4 * t);
        float4 sh = *(const float4*)(shiftp + 4 * t);
        float y0 = ((v0.x - mean) * rstd) * (1.f + sc.x) + sh.x;
        float y1 = ((v0.y - mean) * rstd) * (1.f + sc.y) + sh.y;
        float y2 = ((v0.z - mean) * rstd) * (1.f + sc.z) + sh.z;
        float y3 = ((v0.w - mean) * rstd) * (1.f + sc.w) + sh.w;
        uint2 o; o.x = pack2(y0, y1); o.y = pack2(y2, y3);
        *(uint2*)(out + row * HID + 4 * t) = o;
    }
    if (t < 32) {
        int col = 1024 + 4 * t;
        float4 sc = *(const float4*)(scalep + col);
        float4 sh = *(const float4*)(shiftp + col);
        float y0 = ((v1.x - mean) * rstd) * (1.f + sc.x) + sh.x;
        float y1 = ((v1.y - mean) * rstd) * (1.f + sc.y) + sh.y;
        float y2 = ((v1.z - mean) * rstd) * (1.f + sc.z) + sh.z;
        float y3 = ((v1.w - mean) * rstd) * (1.f + sc.w) + sh.w;
        uint2 o; o.x = pack2(y0, y1); o.y = pack2(y2, y3);
        *(uint2*)(out + row * HID + col) = o;
    }
}

// ---------------- bf16 MFMA GEMM: C = A(M,K) * BT(N,K)^T + bias ----------------
// EPI 0: out fp32 = acc + bias
// EPI 1: out bf16 = gelu(acc + bias)
// EPI 2: out fp32 = resid + gate[b,col]*(acc + bias)   (b from global row r0+row)
DEV int lds_swz(int row, int kg) {   // byte offset in 8KB tile (bijective XOR swizzle)
    return (row << 6) ^ ((row & 7) << 4) ^ (kg << 4);
}

template <int EPI>
__global__ __launch_bounds__(256) void k_gemm_bt(
        const unsigned short* __restrict__ A, const unsigned short* __restrict__ BT,
        const float* __restrict__ bias, void* __restrict__ outp,
        const float* __restrict__ resid, const float* __restrict__ gate,
        int Np, int K, int r0) {
    __shared__ __align__(16) char As[8192];
    __shared__ __align__(16) char Bs[8192];
    const int tid = threadIdx.x;
    const int lane = tid & 63;
    const int wave = tid >> 6;
    const int wr = wave >> 1, wc = wave & 1;
    const int m0 = blockIdx.y << 7;
    const int n0 = blockIdx.x << 7;

    // staging: thread handles rows srow and srow+64, k-group scg (16B each)
    const int srow = tid >> 2;
    const int scg  = tid & 3;
    const unsigned short* aP = A  + (size_t)(m0 + srow) * K + scg * 8;
    const unsigned short* bP = BT + (size_t)(n0 + srow) * K + scg * 8;
    const size_t rstep = (size_t)64 * K;
    const int w0 = lds_swz(srow, scg);
    const int w1 = lds_swz(srow + 64, scg);

    // fragment read offsets (loop invariant)
    const int kg = lane >> 4;
    int aoff[4], boff[4];
    #pragma unroll
    for (int i = 0; i < 4; i++) {
        aoff[i] = lds_swz(wr * 64 + i * 16 + (lane & 15), kg);
        boff[i] = lds_swz(wc * 64 + i * 16 + (lane & 15), kg);
    }

    f32x4 acc[4][4];
    #pragma unroll
    for (int i = 0; i < 4; i++)
        #pragma unroll
        for (int j = 0; j < 4; j++)
            acc[i][j] = (f32x4){0.f, 0.f, 0.f, 0.f};

    uint4 ra0 = *(const uint4*)aP;
    uint4 ra1 = *(const uint4*)(aP + rstep);
    uint4 rb0 = *(const uint4*)bP;
    uint4 rb1 = *(const uint4*)(bP + rstep);

    const int nk = K >> 5;
    for (int kt = 0; kt < nk; ++kt) {
        __syncthreads();
        *(uint4*)(As + w0) = ra0;
        *(uint4*)(As + w1) = ra1;
        *(uint4*)(Bs + w0) = rb0;
        *(uint4*)(Bs + w1) = rb1;
        __syncthreads();
        if (kt + 1 < nk) {
            aP += 32; bP += 32;
            ra0 = *(const uint4*)aP;
            ra1 = *(const uint4*)(aP + rstep);
            rb0 = *(const uint4*)bP;
            rb1 = *(const uint4*)(bP + rstep);
        }
        short8 af[4], bfr[4];
        #pragma unroll
        for (int i = 0; i < 4; i++) af[i]  = *(const short8*)(As + aoff[i]);
        #pragma unroll
        for (int i = 0; i < 4; i++) bfr[i] = *(const short8*)(Bs + boff[i]);
        #pragma unroll
        for (int i = 0; i < 4; i++)
            #pragma unroll
            for (int j = 0; j < 4; j++)
                acc[i][j] = __builtin_amdgcn_mfma_f32_16x16x32_bf16(af[i], bfr[j], acc[i][j], 0, 0, 0);
    }

    // epilogue. C/D layout: col = lane&15, row = 4*(lane>>4)+reg
    const int c_l = lane & 15;
    const int r_l = (lane >> 4) << 2;
    #pragma unroll
    for (int j = 0; j < 4; j++) {
        const int fcol = n0 + wc * 64 + j * 16 + c_l;
        const float bv = bias[fcol];
        #pragma unroll
        for (int i = 0; i < 4; i++) {
            const int frow = m0 + wr * 64 + i * 16 + r_l;
            #pragma unroll
            for (int r = 0; r < 4; r++) {
                float v = acc[i][j][r] + bv;
                const size_t off = (size_t)(frow + r) * Np + fcol;
                if constexpr (EPI == 0) {
                    ((float*)outp)[off] = v;
                } else if constexpr (EPI == 1) {
                    ((unsigned short*)outp)[off] = f2bf16u(gelu_tanh(v));
                } else {
                    const int bb = (r0 + frow + r) >> 10;
                    ((float*)outp)[off] = resid[off] + gate[(size_t)bb * MODW + fcol] * v;
                }
            }
        }
    }
}

// ---------------- focused() norm scales for q (12 heads) and k (4 heads) ----------------
// ql/kvl are chunk bases; scales written at global batch index b0 + local b.
__global__ __launch_bounds__(256) void k_fnorms(const float* __restrict__ ql,
                                                const float* __restrict__ kvl,
                                                float* __restrict__ qscale,
                                                float* __restrict__ kscale,
                                                int b0) {
    const int b = blockIdx.x >> 4, hh = blockIdx.x & 15;
    const float* base;
    int stride;
    if (hh < HEADS) { base = ql  + (size_t)b * SEQ * HID + hh * HD;           stride = HID; }
    else            { base = kvl + (size_t)b * SEQ * (2*KVC) + (hh-HEADS)*HD; stride = 2*KVC; }
    float s2 = 0.f, s6 = 0.f;
    for (int i = threadIdx.x; i < SEQ * (HD / 4); i += 256) {
        int n = i / 24, dq = i % 24;
        float4 v = *(const float4*)(base + (size_t)n * stride + dq * 4);
        float a;
        a = fmaxf(v.x, 0.f); { float a2 = a*a; s2 += a2; s6 += a2*a2*a2; }
        a = fmaxf(v.y, 0.f); { float a2 = a*a; s2 += a2; s6 += a2*a2*a2; }
        a = fmaxf(v.z, 0.f); { float a2 = a*a; s2 += a2; s6 += a2*a2*a2; }
        a = fmaxf(v.w, 0.f); { float a2 = a*a; s2 += a2; s6 += a2*a2*a2; }
    }
    block_reduce2(s2, s6);
    if (threadIdx.x == 0) {
        float an  = sqrtf(s2);
        float apn = (s6 == 0.f) ? 1e-12f : sqrtf(s6);
        float sc = an / apn;
        if (hh < HEADS) qscale[(b0 + b) * HEADS + hh] = sc;
        else            kscale[(b0 + b) * KVH + (hh - HEADS)] = sc;
    }
}

// ---------------- depthwise 3x3 conv on v (32x32 image), out bf16 (b,n,c) chunk-local ----------------
__global__ __launch_bounds__(256) void k_dwconv(const float* __restrict__ kvl,
                                                const float* __restrict__ w,
                                                const float* __restrict__ bias,
                                                unsigned short* __restrict__ vd) {
    const size_t idx = (size_t)blockIdx.x * 256 + threadIdx.x;  // < CB*1024*384
    const int c = (int)(idx % KVC);
    const size_t bn = idx / KVC;
    const int n = (int)(bn & 1023);
    const int b = (int)(bn >> 10);
    const int y = n >> 5, xx = n & 31;
    const float* wc = w + c * 9;
    float acc = bias[c];
    #pragma unroll
    for (int dy = -1; dy <= 1; dy++) {
        int yy = y + dy;
        if (yy < 0 || yy > 31) continue;
        #pragma unroll
        for (int dx = -1; dx <= 1; dx++) {
            int xc = xx + dx;
            if (xc < 0 || xc > 31) continue;
            float v = kvl[((size_t)b * SEQ + yy * 32 + xc) * (2*KVC) + KVC + c];
            acc += wc[(dy + 1) * 3 + (dx + 1)] * v;
        }
    }
    vd[idx] = f2bf16u(acc);
}

// ---------------- kvmat = focused(k)^T @ v  (per local b, kv-head: 96x96) ----------------
__global__ __launch_bounds__(256) void k_kvmat(const float* __restrict__ kvl,
                                               const float* __restrict__ kscale,
                                               float* __restrict__ kvmat,
                                               int b0) {
    const int b = blockIdx.x >> 2, h = blockIdx.x & 3;
    const float sc = kscale[(b0 + b) * KVH + h];
    __shared__ float Ks[16][96], Vs[16][96];
    float acc[6][6];
    #pragma unroll
    for (int i = 0; i < 6; i++)
        #pragma unroll
        for (int j = 0; j < 6; j++) acc[i][j] = 0.f;
    const int ti = threadIdx.x >> 4, tj = threadIdx.x & 15;
    const float* kbase = kvl + (size_t)b * SEQ * (2*KVC) + h * HD;
    const float* vbase = kbase + KVC;
    for (int n0 = 0; n0 < SEQ; n0 += 16) {
        __syncthreads();
        for (int i = threadIdx.x; i < 16 * 96; i += 256) {
            int nn = i / 96, d = i % 96;
            float kv_ = kbase[(size_t)(n0 + nn) * (2*KVC) + d];
            float r = fmaxf(kv_, 0.f);
            Ks[nn][d] = sc * r * r * r;
            Vs[nn][d] = vbase[(size_t)(n0 + nn) * (2*KVC) + d];
        }
        __syncthreads();
        for (int nn = 0; nn < 16; nn++) {
            float av[6], bv[6];
            #pragma unroll
            for (int i = 0; i < 6; i++) av[i] = Ks[nn][ti * 6 + i];
            #pragma unroll
            for (int j = 0; j < 6; j++) bv[j] = Vs[nn][tj * 6 + j];
            #pragma unroll
            for (int i = 0; i < 6; i++)
                #pragma unroll
                for (int j = 0; j < 6; j++) acc[i][j] += av[i] * bv[j];
        }
    }
    float* out = kvmat + (size_t)(b * KVH + h) * 96 * 96;
    #pragma unroll
    for (int i = 0; i < 6; i++)
        #pragma unroll
        for (int j = 0; j < 6; j++)
            out[(size_t)(ti * 6 + i) * 96 + tj * 6 + j] = acc[i][j];
}

// ---------------- o = focused(q) @ kvmat[h%4] + vd[h%4], out bf16 chunk-local ----------------
__global__ __launch_bounds__(256) void k_ogemm(const float* __restrict__ ql,
                                               const float* __restrict__ qscale,
                                               const float* __restrict__ kvmat,
                                               const unsigned short* __restrict__ vd,
                                               unsigned short* __restrict__ obuf,
                                               int b0) {
    const int rc = blockIdx.x;   // 0..7 row chunks of 128
    const int h  = blockIdx.y;   // 0..11
    const int b  = blockIdx.z;   // local batch
    const int kvh = h & 3;
    __shared__ float Ms[96][96];
    for (int i = threadIdx.x; i < 96 * 96; i += 256)
        Ms[i / 96][i % 96] = kvmat[(size_t)(b * KVH + kvh) * 9216 + i];
    const float qs = qscale[(b0 + b) * HEADS + h];
    __syncthreads();
    const int rowg = threadIdx.x >> 3;  // 0..31 (x4 rows)
    const int colg = threadIdx.x & 7;   // 0..7  (x12 cols)
    const int n_base = rc * 128 + rowg * 4;
    const float* qb = ql + ((size_t)(b * SEQ + n_base)) * HID + h * HD;
    float acc[4][12];
    #pragma unroll
    for (int r = 0; r < 4; r++)
        #pragma unroll
        for (int j = 0; j < 12; j++) acc[r][j] = 0.f;
    for (int k = 0; k < 96; k++) {
        float bv[12];
        #pragma unroll
        for (int j = 0; j < 12; j += 4) {
            float4 t = *(const float4*)&Ms[k][colg * 12 + j];
            bv[j] = t.x; bv[j+1] = t.y; bv[j+2] = t.z; bv[j+3] = t.w;
        }
        #pragma unroll
        for (int r = 0; r < 4; r++) {
            float q = qb[(size_t)r * HID + k];
            q = fmaxf(q, 0.f);
            q = qs * q * q * q;
            #pragma unroll
            for (int j = 0; j < 12; j++) acc[r][j] += q * bv[j];
        }
    }
    const unsigned short* vdb = vd + ((size_t)(b * SEQ + n_base)) * KVC + kvh * HD + colg * 12;
    unsigned short* ob = obuf + ((size_t)(b * SEQ + n_base)) * HID + h * HD + colg * 12;
    for (int r = 0; r < 4; r++)
        for (int j = 0; j < 12; j++) {
            float v = acc[r][j] + bfu2f(vdb[(size_t)r * KVC + j]);
            ob[(size_t)r * HID + j] = f2bf16u(v);
        }
}

// ---------------- fixed workspace layout ----------------
constexpr size_t WQT_OFF  = 0;                                    // 1152*1152 bf16
constexpr size_t WKVT_OFF = WQT_OFF  + (size_t)1152*1152*2;       // 768*1152 bf16
constexpr size_t WPT_OFF  = WKVT_OFF + (size_t)768*1152*2;        // 1152*1152 bf16
constexpr size_t W1T_OFF  = WPT_OFF  + (size_t)1152*1152*2;       // 4608*1152 bf16
constexpr size_t W2T_OFF  = W1T_OFF  + (size_t)4608*1152*2;       // 1152*4608 bf16
constexpr size_t MOD_OFF  = W2T_OFF  + (size_t)1152*4608*2;       // 32*6912 f32
constexpr size_t QSC_OFF  = MOD_OFF  + (size_t)BB*MODW*4;         // 32*12 f32
constexpr size_t KSC_OFF  = QSC_OFF  + 1536;                      // 32*4 f32
constexpr size_t DYN_OFF  = KSC_OFF  + 512;                       // chunked scratch

extern "C" void kernel_launch(void* const* d_in, const int* in_sizes, int n_in,
                              void* d_out, int out_size, void* d_ws, size_t ws_size,
                              hipStream_t stream) {
    (void)in_sizes; (void)n_in; (void)out_size;

    const float* x       = (const float*)d_in[0];
    const float* cvec    = (const float*)d_in[1];
    const float* wq_w    = (const float*)d_in[2];
    const float* wq_b    = (const float*)d_in[3];
    const float* wkv_w   = (const float*)d_in[4];
    const float* wkv_b   = (const float*)d_in[5];
    const float* dwc_w   = (const float*)d_in[6];
    const float* dwc_b   = (const float*)d_in[7];
    const float* proj_w  = (const float*)d_in[8];
    const float* proj_b  = (const float*)d_in[9];
    const float* adaln_w = (const float*)d_in[10];
    const float* adaln_b = (const float*)d_in[11];
    const float* mlp_w1  = (const float*)d_in[12];
    const float* mlp_b1  = (const float*)d_in[13];
    const float* mlp_w2  = (const float*)d_in[14];
    const float* mlp_b2  = (const float*)d_in[15];

    // ---- adaptive chunk size: largest CB batches whose scratch fits ws_size ----
    int CB = 0;
    for (int cb = 32; cb >= 1; cb >>= 1) {
        size_t rows = (size_t)cb * 1024;
        size_t attn = rows * (1152*2       /*XM bf16*/
                            + 1152*4       /*QL f32*/
                            + 768*4        /*KVL f32*/
                            + 384*2        /*VD bf16*/
                            + 1152*2)      /*OBUF bf16*/
                    + (size_t)cb * 4 * 9216 * 4;  /*KVM f32*/
        size_t mlp  = rows * (1152*2 + 4608*2);   /*XM2 + H bf16*/
        size_t need = DYN_OFF + (attn > mlp ? attn : mlp);
        if (need <= ws_size) { CB = cb; break; }
    }
    if (CB == 0) return;  // < ~43 MB scratch: cannot run
    const size_t CROWS = (size_t)CB * 1024;

    char* ws = (char*)d_ws;
    unsigned short* WQT  = (unsigned short*)(ws + WQT_OFF);
    unsigned short* WKVT = (unsigned short*)(ws + WKVT_OFF);
    unsigned short* WPT  = (unsigned short*)(ws + WPT_OFF);
    unsigned short* W1T  = (unsigned short*)(ws + W1T_OFF);
    unsigned short* W2T  = (unsigned short*)(ws + W2T_OFF);
    float*          MODp = (float*)(ws + MOD_OFF);
    float*          QSC  = (float*)(ws + QSC_OFF);
    float*          KSC  = (float*)(ws + KSC_OFF);
    // dynamic chunk buffers (attn phase)
    char* dyn = ws + DYN_OFF;
    unsigned short* XMc  = (unsigned short*)dyn;
    float*          QLc  = (float*)(dyn + CROWS * 1152 * 2);
    float*          KVLc = (float*)((char*)QLc + CROWS * 1152 * 4);
    float*          KVMc = (float*)((char*)KVLc + CROWS * 768 * 4);
    unsigned short* VDc  = (unsigned short*)((char*)KVMc + (size_t)CB * 4 * 9216 * 4);
    unsigned short* OBc  = (unsigned short*)((char*)VDc + CROWS * 384 * 2);
    // mlp phase aliases the same region
    unsigned short* XM2  = (unsigned short*)dyn;
    unsigned short* Hc   = (unsigned short*)(dyn + CROWS * 1152 * 2);
    float*          OUT  = (float*)d_out;

    dim3 tb(32, 8);
    k_transpose_bf16<<<dim3(36, 36),  tb, 0, stream>>>(wq_w,   WQT,  1152, 1152);
    k_transpose_bf16<<<dim3(36, 24),  tb, 0, stream>>>(wkv_w,  WKVT, 1152, 768);
    k_transpose_bf16<<<dim3(36, 36),  tb, 0, stream>>>(proj_w, WPT,  1152, 1152);
    k_transpose_bf16<<<dim3(36, 144), tb, 0, stream>>>(mlp_w1, W1T,  1152, 4608);
    k_transpose_bf16<<<dim3(144, 36), tb, 0, stream>>>(mlp_w2, W2T,  4608, 1152);

    k_mod<<<dim3(27, 32), 256, 0, stream>>>(cvec, adaln_w, adaln_b, MODp);

    const int MB = (int)(CROWS >> 7);  // 128-row blocks per chunk

    // --- attention branch, chunked over batches ---
    for (int b0 = 0; b0 < BB; b0 += CB) {
        const int r0 = b0 << 10;
        const float* xch = x + (size_t)r0 * HID;
        k_ln_mod<<<(int)CROWS, 256, 0, stream>>>(xch, MODp, 0, 1, XMc, r0);
        k_gemm_bt<0><<<dim3(9, MB), 256, 0, stream>>>(XMc, WQT,  wq_b,  QLc,  nullptr, nullptr, 1152, 1152, 0);
        k_gemm_bt<0><<<dim3(6, MB), 256, 0, stream>>>(XMc, WKVT, wkv_b, KVLc, nullptr, nullptr, 768,  1152, 0);
        k_fnorms<<<CB * 16, 256, 0, stream>>>(QLc, KVLc, QSC, KSC, b0);
        k_dwconv<<<CB * 1536, 256, 0, stream>>>(KVLc, dwc_w, dwc_b, VDc);
        k_kvmat<<<CB * 4, 256, 0, stream>>>(KVLc, KSC, KVMc, b0);
        k_ogemm<<<dim3(8, HEADS, CB), 256, 0, stream>>>(QLc, QSC, KVMc, VDc, OBc, b0);
        k_gemm_bt<2><<<dim3(9, MB), 256, 0, stream>>>(OBc, WPT, proj_b, OUT + (size_t)r0 * HID,
                                                      xch, MODp + 2 * HID, 1152, 1152, r0);
    }

    // --- MLP branch, chunked over rows (d_out now holds x1 = x + gate*attn) ---
    for (int r0 = 0; r0 < ROWS; r0 += (int)CROWS) {
        float* x1ch = OUT + (size_t)r0 * HID;
        k_ln_mod<<<(int)CROWS, 256, 0, stream>>>(x1ch, MODp, 3, 4, XM2, r0);
        k_gemm_bt<1><<<dim3(36, MB), 256, 0, stream>>>(XM2, W1T, mlp_b1, Hc, nullptr, nullptr, 4608, 1152, 0);
        k_gemm_bt<2><<<dim3(9, MB), 256, 0, stream>>>(Hc, W2T, mlp_b2, x1ch,
                                                      x1ch, MODp + 5 * HID, 1152, 4608, r0);
    }
}

// Round 3
// 2376.059 us; speedup vs baseline: 1.0934x; 1.0934x over previous
//
#include <hip/hip_runtime.h>
#include <hip/hip_bf16.h>
#include <cstdint>
#include <cstddef>

#define DEV __device__ __forceinline__

// ---------------- problem constants ----------------
constexpr int BB    = 32;
constexpr int SEQ   = 1024;
constexpr int HID   = 1152;
constexpr int HEADS = 12;
constexpr int KVH   = 4;
constexpr int HD    = 96;
constexpr int KVC   = 384;   // KVH*HD
constexpr int MLPD  = 4608;
constexpr int ROWS  = BB * SEQ;          // 32768
constexpr int MODW  = 6 * HID;           // 6912

typedef __attribute__((ext_vector_type(8))) short short8;
typedef __attribute__((ext_vector_type(4))) float f32x4;

// ---------------- helpers ----------------
DEV float bfu2f(unsigned short u) {
    unsigned v = ((unsigned)u) << 16;
    return __builtin_bit_cast(float, v);
}
DEV unsigned short f2bf16u(float f) {
    unsigned u = __builtin_bit_cast(unsigned, f);
    u += 0x7FFFu + ((u >> 16) & 1u);   // RNE
    return (unsigned short)(u >> 16);
}
DEV unsigned pack2(float a, float b) {
    return (unsigned)f2bf16u(a) | ((unsigned)f2bf16u(b) << 16);
}
DEV float gelu_tanh(float x) {
    float x3 = x * x * x;
    float t = tanhf(0.7978845608028654f * (x + 0.044715f * x3));
    return 0.5f * x * (1.f + t);
}

// async global->LDS, 16B per lane. LDS dest must be wave-uniform base (+lane*16).
DEV void gload16(const void* g, void* l) {
    __builtin_amdgcn_global_load_lds(
        (const __attribute__((address_space(1))) unsigned int*)g,
        (__attribute__((address_space(3))) unsigned int*)l,
        16, 0, 0);
}

// block reduce of two floats, blockDim.x == 256
DEV void block_reduce2(float& a, float& b) {
    #pragma unroll
    for (int off = 32; off > 0; off >>= 1) {
        a += __shfl_down(a, off, 64);
        b += __shfl_down(b, off, 64);
    }
    __shared__ float sa[4], sb[4];
    int w = threadIdx.x >> 6;
    if ((threadIdx.x & 63) == 0) { sa[w] = a; sb[w] = b; }
    __syncthreads();
    a = sa[0] + sa[1] + sa[2] + sa[3];
    b = sb[0] + sb[1] + sb[2] + sb[3];
    __syncthreads();
}

// ---------------- weight transpose + bf16 convert ----------------
// in: fp32 (K,N) row-major -> out: bf16 (N,K) row-major
__global__ void k_transpose_bf16(const float* __restrict__ in,
                                 unsigned short* __restrict__ out, int K, int N) {
    __shared__ float tile[32][33];
    int kb = blockIdx.x * 32;
    int nb = blockIdx.y * 32;
    int tx = threadIdx.x, ty = threadIdx.y;   // (32, 8)
    #pragma unroll
    for (int j = 0; j < 4; j++) {
        int k = kb + ty + j * 8;
        tile[ty + j * 8][tx] = (k < K && nb + tx < N) ? in[(size_t)k * N + nb + tx] : 0.f;
    }
    __syncthreads();
    #pragma unroll
    for (int j = 0; j < 4; j++) {
        int n = nb + ty + j * 8;
        if (n < N && kb + tx < K)
            out[(size_t)n * K + kb + tx] = f2bf16u(tile[tx][ty + j * 8]);
    }
}

// ---------------- adaLN: mod = silu(c) @ adaln_w + adaln_b ----------------
// grid (27, 4): 256-col chunk x 8-batch group; w read 4x instead of 32x.
__global__ __launch_bounds__(256) void k_mod(const float* __restrict__ cvec,
                                             const float* __restrict__ w,
                                             const float* __restrict__ bias,
                                             float* __restrict__ mod) {
    const int col = blockIdx.x * 256 + threadIdx.x;
    const int bg = blockIdx.y * 8;
    __shared__ float sc[8][HID];
    for (int t = threadIdx.x; t < 8 * HID; t += 256) {
        int bb = t / HID, k = t % HID;
        float v = cvec[(bg + bb) * HID + k];
        sc[bb][k] = v / (1.f + __expf(-v));
    }
    __syncthreads();
    float acc[8];
    const float bv = bias[col];
    #pragma unroll
    for (int b = 0; b < 8; b++) acc[b] = bv;
    for (int k = 0; k < HID; k++) {
        float wv = w[(size_t)k * MODW + col];
        #pragma unroll
        for (int b = 0; b < 8; b++) acc[b] += sc[b][k] * wv;
    }
    #pragma unroll
    for (int b = 0; b < 8; b++) mod[(size_t)(bg + b) * MODW + col] = acc[b];
}

// ---------------- layernorm + modulate -> bf16 ----------------
// x is a CHUNK base (row 0 = global row r0); out is chunk base.
__global__ __launch_bounds__(256) void k_ln_mod(const float* __restrict__ x,
                                                const float* __restrict__ mod,
                                                int shift_chunk, int scale_chunk,
                                                unsigned short* __restrict__ out,
                                                int r0) {
    const size_t row = blockIdx.x;
    const int b = (int)((r0 + row) >> 10);
    const float4* xr = (const float4*)(x + row * HID);
    const int t = threadIdx.x;
    float4 v0 = xr[t];
    float4 v1 = make_float4(0.f, 0.f, 0.f, 0.f);
    if (t < 32) v1 = xr[256 + t];
    float s  = v0.x + v0.y + v0.z + v0.w + v1.x + v1.y + v1.z + v1.w;
    float s2 = v0.x*v0.x + v0.y*v0.y + v0.z*v0.z + v0.w*v0.w
             + v1.x*v1.x + v1.y*v1.y + v1.z*v1.z + v1.w*v1.w;
    block_reduce2(s, s2);
    const float mean = s * (1.f / HID);
    float var = s2 * (1.f / HID) - mean * mean;
    const float rstd = rsqrtf(fmaxf(var, 0.f) + 1e-6f);
    const float* shiftp = mod + (size_t)b * MODW + shift_chunk * HID;
    const float* scalep = mod + (size_t)b * MODW + scale_chunk * HID;
    {
        float4 sc = *(const float4*)(scalep + 4 * t);
        float4 sh = *(const float4*)(shiftp + 4 * t);
        float y0 = ((v0.x - mean) * rstd) * (1.f + sc.x) + sh.x;
        float y1 = ((v0.y - mean) * rstd) * (1.f + sc.y) + sh.y;
        float y2 = ((v0.z - mean) * rstd) * (1.f + sc.z) + sh.z;
        float y3 = ((v0.w - mean) * rstd) * (1.f + sc.w) + sh.w;
        uint2 o; o.x = pack2(y0, y1); o.y = pack2(y2, y3);
        *(uint2*)(out + row * HID + 4 * t) = o;
    }
    if (t < 32) {
        int col = 1024 + 4 * t;
        float4 sc = *(const float4*)(scalep + col);
        float4 sh = *(const float4*)(shiftp + col);
        float y0 = ((v1.x - mean) * rstd) * (1.f + sc.x) + sh.x;
        float y1 = ((v1.y - mean) * rstd) * (1.f + sc.y) + sh.y;
        float y2 = ((v1.z - mean) * rstd) * (1.f + sc.z) + sh.z;
        float y3 = ((v1.w - mean) * rstd) * (1.f + sc.w) + sh.w;
        uint2 o; o.x = pack2(y0, y1); o.y = pack2(y2, y3);
        *(uint2*)(out + row * HID + col) = o;
    }
}

// ---------------- bf16 MFMA GEMM: C = A(M,K) * BT(N,K)^T + bias ----------------
// 128x128 tile, BK=64, global_load_lds staging (linear LDS dest, source-swizzled),
// swizzled ds_read (4-way max). 2 barriers per K-step (m97 structure).
// EPI 0: out fp32 = acc + bias
// EPI 1: out bf16 = gelu(acc + bias)
// EPI 2: out fp32 = resid + gate[b,col]*(acc + bias)   (b from global row r0+row)
template <int EPI>
__global__ __launch_bounds__(256, 4) void k_gemm_bt(
        const unsigned short* __restrict__ A, const unsigned short* __restrict__ BT,
        const float* __restrict__ bias, void* __restrict__ outp,
        const float* __restrict__ resid, const float* __restrict__ gate,
        int Np, int K, int r0) {
    // LDS tiles: [128 rows][64 k] bf16 = 16KB each, row = 128B.
    // Within-row swizzle: 16B slot s holds k-group kg = s ^ (row&7).
    __shared__ __align__(16) char As[16384];
    __shared__ __align__(16) char Bs[16384];
    const int tid  = threadIdx.x;
    const int lane = tid & 63;
    const int wave = tid >> 6;
    const int wr = wave >> 1, wc = wave & 1;
    const int m0 = blockIdx.y << 7;
    const int n0 = blockIdx.x << 7;

    // staging: wave w covers rows 32w..32w+31 (4 chunks of 8 rows = 1KB each).
    // lane i in a chunk: row = base + (i>>3), slot = i&7, kg = slot ^ (row&7).
    const int srow = lane >> 3;                 // 0..7
    const int kgrp = (lane & 7) ^ srow;         // swizzled k-group for this lane
    const unsigned short* aS = A  + (size_t)(m0 + 32 * wave + srow) * K + kgrp * 8;
    const unsigned short* bS = BT + (size_t)(n0 + 32 * wave + srow) * K + kgrp * 8;
    const size_t chunkK = (size_t)8 * K;        // 8 rows per chunk
    char* aD = As + wave * 4096;
    char* bD = Bs + wave * 4096;

    // fragment read offsets (kk=0): r = w?*64 + i*16 + (lane&15), kg = lane>>4
    // byte = r*128 + ((kg ^ (r&7))<<4); kk=1 toggles kg bit2 -> byte ^ 64
    const int hi = lane >> 4;
    const int lo = lane & 15;
    const int swz = ((hi ^ (lo & 7)) << 4);
    int aoff[4], boff[4];
    #pragma unroll
    for (int i = 0; i < 4; i++) {
        aoff[i] = (wr * 64 + i * 16 + lo) * 128 + swz;
        boff[i] = (wc * 64 + i * 16 + lo) * 128 + swz;
    }

    f32x4 acc[4][4];
    #pragma unroll
    for (int i = 0; i < 4; i++)
        #pragma unroll
        for (int j = 0; j < 4; j++)
            acc[i][j] = (f32x4){0.f, 0.f, 0.f, 0.f};

    const int nk = K >> 6;
    for (int kt = 0; kt < nk; ++kt) {
        __syncthreads();   // prior iteration's ds_reads done -> LDS reusable
        #pragma unroll
        for (int j = 0; j < 4; j++) {
            gload16(aS + j * chunkK, aD + j * 1024);
            gload16(bS + j * chunkK, bD + j * 1024);
        }
        aS += 64; bS += 64;
        __syncthreads();   // vmcnt(0) drained before barrier -> tiles ready
        #pragma unroll
        for (int kk = 0; kk < 2; kk++) {
            const int kx = kk << 6;
            short8 bfr[4];
            #pragma unroll
            for (int j = 0; j < 4; j++)
                bfr[j] = *(const short8*)(Bs + (boff[j] ^ kx));
            #pragma unroll
            for (int i = 0; i < 4; i++) {
                short8 af = *(const short8*)(As + (aoff[i] ^ kx));
                #pragma unroll
                for (int j = 0; j < 4; j++)
                    acc[i][j] = __builtin_amdgcn_mfma_f32_16x16x32_bf16(af, bfr[j], acc[i][j], 0, 0, 0);
            }
        }
    }

    // epilogue. C/D layout: col = lane&15, row = 4*(lane>>4)+reg
    const int c_l = lane & 15;
    const int r_l = (lane >> 4) << 2;
    #pragma unroll
    for (int j = 0; j < 4; j++) {
        const int fcol = n0 + wc * 64 + j * 16 + c_l;
        const float bv = bias[fcol];
        #pragma unroll
        for (int i = 0; i < 4; i++) {
            const int frow = m0 + wr * 64 + i * 16 + r_l;
            #pragma unroll
            for (int r = 0; r < 4; r++) {
                float v = acc[i][j][r] + bv;
                const size_t off = (size_t)(frow + r) * Np + fcol;
                if constexpr (EPI == 0) {
                    ((float*)outp)[off] = v;
                } else if constexpr (EPI == 1) {
                    ((unsigned short*)outp)[off] = f2bf16u(gelu_tanh(v));
                } else {
                    const int bb = (r0 + frow + r) >> 10;
                    ((float*)outp)[off] = resid[off] + gate[(size_t)bb * MODW + fcol] * v;
                }
            }
        }
    }
}

// ---------------- focused() norm scales for q (12 heads) and k (4 heads) ----------------
// ql/kvl are chunk bases; scales written at global batch index b0 + local b.
__global__ __launch_bounds__(256) void k_fnorms(const float* __restrict__ ql,
                                                const float* __restrict__ kvl,
                                                float* __restrict__ qscale,
                                                float* __restrict__ kscale,
                                                int b0) {
    const int b = blockIdx.x >> 4, hh = blockIdx.x & 15;
    const float* base;
    int stride;
    if (hh < HEADS) { base = ql  + (size_t)b * SEQ * HID + hh * HD;           stride = HID; }
    else            { base = kvl + (size_t)b * SEQ * (2*KVC) + (hh-HEADS)*HD; stride = 2*KVC; }
    float s2 = 0.f, s6 = 0.f;
    for (int i = threadIdx.x; i < SEQ * (HD / 4); i += 256) {
        int n = i / 24, dq = i % 24;
        float4 v = *(const float4*)(base + (size_t)n * stride + dq * 4);
        float a;
        a = fmaxf(v.x, 0.f); { float a2 = a*a; s2 += a2; s6 += a2*a2*a2; }
        a = fmaxf(v.y, 0.f); { float a2 = a*a; s2 += a2; s6 += a2*a2*a2; }
        a = fmaxf(v.z, 0.f); { float a2 = a*a; s2 += a2; s6 += a2*a2*a2; }
        a = fmaxf(v.w, 0.f); { float a2 = a*a; s2 += a2; s6 += a2*a2*a2; }
    }
    block_reduce2(s2, s6);
    if (threadIdx.x == 0) {
        float an  = sqrtf(s2);
        float apn = (s6 == 0.f) ? 1e-12f : sqrtf(s6);
        float sc = an / apn;
        if (hh < HEADS) qscale[(b0 + b) * HEADS + hh] = sc;
        else            kscale[(b0 + b) * KVH + (hh - HEADS)] = sc;
    }
}

// ---------------- depthwise 3x3 conv on v (32x32 image), out bf16 (b,n,c) chunk-local ----------------
__global__ __launch_bounds__(256) void k_dwconv(const float* __restrict__ kvl,
                                                const float* __restrict__ w,
                                                const float* __restrict__ bias,
                                                unsigned short* __restrict__ vd) {
    const size_t idx = (size_t)blockIdx.x * 256 + threadIdx.x;  // < CB*1024*384
    const int c = (int)(idx % KVC);
    const size_t bn = idx / KVC;
    const int n = (int)(bn & 1023);
    const int b = (int)(bn >> 10);
    const int y = n >> 5, xx = n & 31;
    const float* wc = w + c * 9;
    float acc = bias[c];
    #pragma unroll
    for (int dy = -1; dy <= 1; dy++) {
        int yy = y + dy;
        if (yy < 0 || yy > 31) continue;
        #pragma unroll
        for (int dx = -1; dx <= 1; dx++) {
            int xc = xx + dx;
            if (xc < 0 || xc > 31) continue;
            float v = kvl[((size_t)b * SEQ + yy * 32 + xc) * (2*KVC) + KVC + c];
            acc += wc[(dy + 1) * 3 + (dx + 1)] * v;
        }
    }
    vd[idx] = f2bf16u(acc);
}

// ---------------- kvmat = focused(k)^T @ v  (per local b, kv-head: 96x96) ----------------
__global__ __launch_bounds__(256) void k_kvmat(const float* __restrict__ kvl,
                                               const float* __restrict__ kscale,
                                               float* __restrict__ kvmat,
                                               int b0) {
    const int b = blockIdx.x >> 2, h = blockIdx.x & 3;
    const float sc = kscale[(b0 + b) * KVH + h];
    __shared__ float Ks[16][96], Vs[16][96];
    float acc[6][6];
    #pragma unroll
    for (int i = 0; i < 6; i++)
        #pragma unroll
        for (int j = 0; j < 6; j++) acc[i][j] = 0.f;
    const int ti = threadIdx.x >> 4, tj = threadIdx.x & 15;
    const float* kbase = kvl + (size_t)b * SEQ * (2*KVC) + h * HD;
    const float* vbase = kbase + KVC;
    for (int n0 = 0; n0 < SEQ; n0 += 16) {
        __syncthreads();
        for (int i = threadIdx.x; i < 16 * 96; i += 256) {
            int nn = i / 96, d = i % 96;
            float kv_ = kbase[(size_t)(n0 + nn) * (2*KVC) + d];
            float r = fmaxf(kv_, 0.f);
            Ks[nn][d] = sc * r * r * r;
            Vs[nn][d] = vbase[(size_t)(n0 + nn) * (2*KVC) + d];
        }
        __syncthreads();
        for (int nn = 0; nn < 16; nn++) {
            float av[6], bv[6];
            #pragma unroll
            for (int i = 0; i < 6; i++) av[i] = Ks[nn][ti * 6 + i];
            #pragma unroll
            for (int j = 0; j < 6; j++) bv[j] = Vs[nn][tj * 6 + j];
            #pragma unroll
            for (int i = 0; i < 6; i++)
                #pragma unroll
                for (int j = 0; j < 6; j++) acc[i][j] += av[i] * bv[j];
        }
    }
    float* out = kvmat + (size_t)(b * KVH + h) * 96 * 96;
    #pragma unroll
    for (int i = 0; i < 6; i++)
        #pragma unroll
        for (int j = 0; j < 6; j++)
            out[(size_t)(ti * 6 + i) * 96 + tj * 6 + j] = acc[i][j];
}

// ---------------- o = focused(q) @ kvmat[h%4] + vd[h%4], out bf16 chunk-local ----------------
__global__ __launch_bounds__(256) void k_ogemm(const float* __restrict__ ql,
                                               const float* __restrict__ qscale,
                                               const float* __restrict__ kvmat,
                                               const unsigned short* __restrict__ vd,
                                               unsigned short* __restrict__ obuf,
                                               int b0) {
    const int rc = blockIdx.x;   // 0..7 row chunks of 128
    const int h  = blockIdx.y;   // 0..11
    const int b  = blockIdx.z;   // local batch
    const int kvh = h & 3;
    __shared__ float Ms[96][96];
    for (int i = threadIdx.x; i < 96 * 96; i += 256)
        Ms[i / 96][i % 96] = kvmat[(size_t)(b * KVH + kvh) * 9216 + i];
    const float qs = qscale[(b0 + b) * HEADS + h];
    __syncthreads();
    const int rowg = threadIdx.x >> 3;  // 0..31 (x4 rows)
    const int colg = threadIdx.x & 7;   // 0..7  (x12 cols)
    const int n_base = rc * 128 + rowg * 4;
    const float* qb = ql + ((size_t)(b * SEQ + n_base)) * HID + h * HD;
    float acc[4][12];
    #pragma unroll
    for (int r = 0; r < 4; r++)
        #pragma unroll
        for (int j = 0; j < 12; j++) acc[r][j] = 0.f;
    for (int k = 0; k < 96; k++) {
        float bv[12];
        #pragma unroll
        for (int j = 0; j < 12; j += 4) {
            float4 t = *(const float4*)&Ms[k][colg * 12 + j];
            bv[j] = t.x; bv[j+1] = t.y; bv[j+2] = t.z; bv[j+3] = t.w;
        }
        #pragma unroll
        for (int r = 0; r < 4; r++) {
            float q = qb[(size_t)r * HID + k];
            q = fmaxf(q, 0.f);
            q = qs * q * q * q;
            #pragma unroll
            for (int j = 0; j < 12; j++) acc[r][j] += q * bv[j];
        }
    }
    const unsigned short* vdb = vd + ((size_t)(b * SEQ + n_base)) * KVC + kvh * HD + colg * 12;
    unsigned short* ob = obuf + ((size_t)(b * SEQ + n_base)) * HID + h * HD + colg * 12;
    for (int r = 0; r < 4; r++)
        for (int j = 0; j < 12; j++) {
            float v = acc[r][j] + bfu2f(vdb[(size_t)r * KVC + j]);
            ob[(size_t)r * HID + j] = f2bf16u(v);
        }
}

// ---------------- fixed workspace layout ----------------
constexpr size_t WQT_OFF  = 0;                                    // 1152*1152 bf16
constexpr size_t WKVT_OFF = WQT_OFF  + (size_t)1152*1152*2;       // 768*1152 bf16
constexpr size_t WPT_OFF  = WKVT_OFF + (size_t)768*1152*2;        // 1152*1152 bf16
constexpr size_t W1T_OFF  = WPT_OFF  + (size_t)1152*1152*2;       // 4608*1152 bf16
constexpr size_t W2T_OFF  = W1T_OFF  + (size_t)4608*1152*2;       // 1152*4608 bf16
constexpr size_t MOD_OFF  = W2T_OFF  + (size_t)1152*4608*2;       // 32*6912 f32
constexpr size_t QSC_OFF  = MOD_OFF  + (size_t)BB*MODW*4;         // 32*12 f32
constexpr size_t KSC_OFF  = QSC_OFF  + 1536;                      // 32*4 f32
constexpr size_t DYN_OFF  = KSC_OFF  + 512;                       // chunked scratch

extern "C" void kernel_launch(void* const* d_in, const int* in_sizes, int n_in,
                              void* d_out, int out_size, void* d_ws, size_t ws_size,
                              hipStream_t stream) {
    (void)in_sizes; (void)n_in; (void)out_size;

    const float* x       = (const float*)d_in[0];
    const float* cvec    = (const float*)d_in[1];
    const float* wq_w    = (const float*)d_in[2];
    const float* wq_b    = (const float*)d_in[3];
    const float* wkv_w   = (const float*)d_in[4];
    const float* wkv_b   = (const float*)d_in[5];
    const float* dwc_w   = (const float*)d_in[6];
    const float* dwc_b   = (const float*)d_in[7];
    const float* proj_w  = (const float*)d_in[8];
    const float* proj_b  = (const float*)d_in[9];
    const float* adaln_w = (const float*)d_in[10];
    const float* adaln_b = (const float*)d_in[11];
    const float* mlp_w1  = (const float*)d_in[12];
    const float* mlp_b1  = (const float*)d_in[13];
    const float* mlp_w2  = (const float*)d_in[14];
    const float* mlp_b2  = (const float*)d_in[15];

    // ---- adaptive chunk size: largest CB batches whose scratch fits ws_size ----
    int CB = 0;
    for (int cb = 32; cb >= 1; cb >>= 1) {
        size_t rows = (size_t)cb * 1024;
        size_t attn = rows * (1152*2       /*XM bf16*/
                            + 1152*4       /*QL f32*/
                            + 768*4        /*KVL f32*/
                            + 384*2        /*VD bf16*/
                            + 1152*2)      /*OBUF bf16*/
                    + (size_t)cb * 4 * 9216 * 4;  /*KVM f32*/
        size_t mlp  = rows * (1152*2 + 4608*2);   /*XM2 + H bf16*/
        size_t need = DYN_OFF + (attn > mlp ? attn : mlp);
        if (need <= ws_size) { CB = cb; break; }
    }
    if (CB == 0) return;  // < ~43 MB scratch: cannot run
    const size_t CROWS = (size_t)CB * 1024;

    char* ws = (char*)d_ws;
    unsigned short* WQT  = (unsigned short*)(ws + WQT_OFF);
    unsigned short* WKVT = (unsigned short*)(ws + WKVT_OFF);
    unsigned short* WPT  = (unsigned short*)(ws + WPT_OFF);
    unsigned short* W1T  = (unsigned short*)(ws + W1T_OFF);
    unsigned short* W2T  = (unsigned short*)(ws + W2T_OFF);
    float*          MODp = (float*)(ws + MOD_OFF);
    float*          QSC  = (float*)(ws + QSC_OFF);
    float*          KSC  = (float*)(ws + KSC_OFF);
    // dynamic chunk buffers (attn phase)
    char* dyn = ws + DYN_OFF;
    unsigned short* XMc  = (unsigned short*)dyn;
    float*          QLc  = (float*)(dyn + CROWS * 1152 * 2);
    float*          KVLc = (float*)((char*)QLc + CROWS * 1152 * 4);
    float*          KVMc = (float*)((char*)KVLc + CROWS * 768 * 4);
    unsigned short* VDc  = (unsigned short*)((char*)KVMc + (size_t)CB * 4 * 9216 * 4);
    unsigned short* OBc  = (unsigned short*)((char*)VDc + CROWS * 384 * 2);
    // mlp phase aliases the same region
    unsigned short* XM2  = (unsigned short*)dyn;
    unsigned short* Hc   = (unsigned short*)(dyn + CROWS * 1152 * 2);
    float*          OUT  = (float*)d_out;

    dim3 tb(32, 8);
    k_transpose_bf16<<<dim3(36, 36),  tb, 0, stream>>>(wq_w,   WQT,  1152, 1152);
    k_transpose_bf16<<<dim3(36, 24),  tb, 0, stream>>>(wkv_w,  WKVT, 1152, 768);
    k_transpose_bf16<<<dim3(36, 36),  tb, 0, stream>>>(proj_w, WPT,  1152, 1152);
    k_transpose_bf16<<<dim3(36, 144), tb, 0, stream>>>(mlp_w1, W1T,  1152, 4608);
    k_transpose_bf16<<<dim3(144, 36), tb, 0, stream>>>(mlp_w2, W2T,  4608, 1152);

    k_mod<<<dim3(27, 4), 256, 0, stream>>>(cvec, adaln_w, adaln_b, MODp);

    const int MB = (int)(CROWS >> 7);  // 128-row blocks per chunk

    // --- attention branch, chunked over batches ---
    for (int b0 = 0; b0 < BB; b0 += CB) {
        const int r0 = b0 << 10;
        const float* xch = x + (size_t)r0 * HID;
        k_ln_mod<<<(int)CROWS, 256, 0, stream>>>(xch, MODp, 0, 1, XMc, r0);
        k_gemm_bt<0><<<dim3(9, MB), 256, 0, stream>>>(XMc, WQT,  wq_b,  QLc,  nullptr, nullptr, 1152, 1152, 0);
        k_gemm_bt<0><<<dim3(6, MB), 256, 0, stream>>>(XMc, WKVT, wkv_b, KVLc, nullptr, nullptr, 768,  1152, 0);
        k_fnorms<<<CB * 16, 256, 0, stream>>>(QLc, KVLc, QSC, KSC, b0);
        k_dwconv<<<CB * 1536, 256, 0, stream>>>(KVLc, dwc_w, dwc_b, VDc);
        k_kvmat<<<CB * 4, 256, 0, stream>>>(KVLc, KSC, KVMc, b0);
        k_ogemm<<<dim3(8, HEADS, CB), 256, 0, stream>>>(QLc, QSC, KVMc, VDc, OBc, b0);
        k_gemm_bt<2><<<dim3(9, MB), 256, 0, stream>>>(OBc, WPT, proj_b, OUT + (size_t)r0 * HID,
                                                      xch, MODp + 2 * HID, 1152, 1152, r0);
    }

    // --- MLP branch, chunked over rows (d_out now holds x1 = x + gate*attn) ---
    for (int r0 = 0; r0 < ROWS; r0 += (int)CROWS) {
        float* x1ch = OUT + (size_t)r0 * HID;
        k_ln_mod<<<(int)CROWS, 256, 0, stream>>>(x1ch, MODp, 3, 4, XM2, r0);
        k_gemm_bt<1><<<dim3(36, MB), 256, 0, stream>>>(XM2, W1T, mlp_b1, Hc, nullptr, nullptr, 4608, 1152, 0);
        k_gemm_bt<2><<<dim3(9, MB), 256, 0, stream>>>(Hc, W2T, mlp_b2, x1ch,
                                                      x1ch, MODp + 5 * HID, 1152, 4608, r0);
    }
}